// Round 1
// baseline (1029.804 us; speedup 1.0000x reference)
//
#include <hip/hip_runtime.h>

#define N_NODES 10000
#define N_EDGESN 160000
#define E_TOT   (N_EDGESN + N_NODES)   // 170000
#define C 128
#define H 8
#define G 16
#define LLAYERS 5
#define NUM_FEAT 14
#define DIM_OUT 16
#define CH 16   // C/H
#define CG 8    // C/G
#define XSTRIDE (6*C)   // x_all row stride (6 layer slots)

__device__ __forceinline__ void atomAddF(float* p, float v) {
    __hip_atomic_fetch_add(p, v, __ATOMIC_RELAXED, __HIP_MEMORY_SCOPE_AGENT);
}

// ---- init: deg = 1 (self loop), agg = 0 ----
__global__ void k_init(float* __restrict__ deg, float* __restrict__ agg) {
    int i = blockIdx.x * blockDim.x + threadIdx.x;
    if (i < N_NODES) deg[i] = 1.0f;
    if (i < N_NODES * C) agg[i] = 0.0f;
}

// ---- degree count over original edges (by col) ----
__global__ void k_deg(const int* __restrict__ col, float* __restrict__ deg) {
    int e = blockIdx.x * blockDim.x + threadIdx.x;
    if (e < N_EDGESN) atomAddF(&deg[col[e]], 1.0f);
}

// ---- deg -> rsqrt(deg) in place ----
__global__ void k_rsqrt(float* __restrict__ deg) {
    int i = blockIdx.x * blockDim.x + threadIdx.x;
    if (i < N_NODES) deg[i] = rsqrtf(deg[i]);
}

// ---- norm[e] = dis[row]*dis[col] over E_TOT edges (self loops appended) ----
__global__ void k_norm(const int* __restrict__ row, const int* __restrict__ col,
                       const float* __restrict__ dis, float* __restrict__ nrm) {
    int e = blockIdx.x * blockDim.x + threadIdx.x;
    if (e >= E_TOT) return;
    int r = (e < N_EDGESN) ? row[e] : (e - N_EDGESN);
    int c = (e < N_EDGESN) ? col[e] : (e - N_EDGESN);
    nrm[e] = dis[r] * dis[c];
}

// ---- lin1: x (n,14) @ w (14,128) + b, relu -> x_all[:,0,:] ----
__global__ __launch_bounds__(256) void k_lin1(const float* __restrict__ x,
                                              const float* __restrict__ w,
                                              const float* __restrict__ b,
                                              float* __restrict__ x_all) {
    __shared__ float sw[NUM_FEAT * C];
    __shared__ float sb[C];
    int tid = threadIdx.x;
    for (int i = tid; i < NUM_FEAT * C; i += 256) sw[i] = w[i];
    if (tid < C) sb[tid] = b[tid];
    __syncthreads();
    int node = blockIdx.x * 2 + tid / C;
    int c = tid & (C - 1);
    if (node >= N_NODES) return;
    const float* xr = x + node * NUM_FEAT;
    float acc = sb[c];
#pragma unroll
    for (int f = 0; f < NUM_FEAT; f++) acc += xr[f] * sw[f * C + c];
    x_all[node * XSTRIDE + c] = fmaxf(acc, 0.0f);
}

// ---- per-node grouped-linear Q/K/V for layer l ----
// grid.y: 0 -> Q (from slot l); 1..l+1 -> K_j (j=y-1); l+2..2l+2 -> V_j
__global__ __launch_bounds__(256) void k_qkv(const float* __restrict__ x_all,
                                             const float* __restrict__ Wq, const float* __restrict__ bq,
                                             const float* __restrict__ Wk, const float* __restrict__ bk,
                                             const float* __restrict__ Wv, const float* __restrict__ bv,
                                             float* __restrict__ Qb, float* __restrict__ Kb,
                                             float* __restrict__ Vb, int l) {
    int m = blockIdx.y;
    int mode, j;
    if (m == 0)           { mode = 0; j = l; }
    else if (m <= l + 1)  { mode = 1; j = m - 1; }
    else                  { mode = 2; j = m - l - 2; }
    const float* W = ((mode == 0) ? Wq : (mode == 1) ? Wk : Wv) + l * (G * CG * CG);
    const float* bias = ((mode == 0) ? bq : (mode == 1) ? bk : bv) + l * C;

    __shared__ float sW[G * CG * CG];   // 1024
    __shared__ float sb[C];
    __shared__ float sx[2][C];
    int tid = threadIdx.x;
    for (int i = tid; i < G * CG * CG; i += 256) sW[i] = W[i];
    if (tid < C) sb[tid] = bias[tid];
    int node = blockIdx.x * 2 + tid / C;
    int c = tid & (C - 1);
    if (node < N_NODES) sx[tid / C][c] = x_all[node * XSTRIDE + j * C + c];
    __syncthreads();
    if (node >= N_NODES) return;
    int g = c >> 3, o = c & 7;
    const float* xr = sx[tid / C] + g * CG;
    const float* wg = sW + g * CG * CG;
    float acc = sb[c];
#pragma unroll
    for (int i = 0; i < CG; i++) acc += xr[i] * wg[i * CG + o];
    if (mode == 0)      Qb[node * C + c] = acc;
    else if (mode == 1) Kb[(node * LLAYERS + j) * C + c] = acc;
    else                Vb[(node * LLAYERS + j) * C + c] = acc;
}

// ---- per-edge attention + scatter. One wave (64 lanes) per edge; lane owns 2 channels ----
template <int NL>
__global__ __launch_bounds__(256) void k_attn(const int* __restrict__ row, const int* __restrict__ col,
                                              const float* __restrict__ nrm,
                                              const float* __restrict__ Qb, const float* __restrict__ Kb,
                                              const float* __restrict__ Vb, float* __restrict__ agg) {
    int wave = (blockIdx.x * blockDim.x + threadIdx.x) >> 6;
    int lane = threadIdx.x & 63;
    if (wave >= E_TOT) return;
    int r = (wave < N_EDGESN) ? row[wave] : (wave - N_EDGESN);
    int cd = (wave < N_EDGESN) ? col[wave] : (wave - N_EDGESN);
    float w_nrm = nrm[wave];
    int c0 = lane * 2;
    const float2 q = *(const float2*)(Qb + cd * C + c0);
    const float* kbase = Kb + (r * LLAYERS) * C + c0;
    const float* vbase = Vb + (r * LLAYERS) * C + c0;
    float s[NL];
    const float scale = 0.25f;   // 1/sqrt(CH=16)
#pragma unroll
    for (int j = 0; j < NL; j++) {
        float2 k = *(const float2*)(kbase + j * C);
        float p = q.x * k.x + q.y * k.y;
        p += __shfl_xor(p, 1);
        p += __shfl_xor(p, 2);
        p += __shfl_xor(p, 4);   // 8 lanes = one 16-ch head
        s[j] = p * scale;
    }
    float mx = s[0];
#pragma unroll
    for (int j = 1; j < NL; j++) mx = fmaxf(mx, s[j]);
    float sum = 0.0f;
#pragma unroll
    for (int j = 0; j < NL; j++) { s[j] = __expf(s[j] - mx); sum += s[j]; }
    float inv = w_nrm / sum;
    float ox = 0.0f, oy = 0.0f;
#pragma unroll
    for (int j = 0; j < NL; j++) {
        float2 v = *(const float2*)(vbase + j * C);
        ox += s[j] * v.x;
        oy += s[j] * v.y;
    }
    atomAddF(&agg[cd * C + c0],     ox * inv);
    atomAddF(&agg[cd * C + c0 + 1], oy * inv);
}

// ---- relu(agg) -> x_all[:, l+1]; re-zero agg ----
__global__ void k_relu_store(float* __restrict__ x_all, float* __restrict__ agg, int l) {
    int i = blockIdx.x * blockDim.x + threadIdx.x;
    if (i >= N_NODES * C) return;
    int node = i >> 7, c = i & (C - 1);
    float v = agg[i];
    x_all[node * XSTRIDE + (l + 1) * C + c] = fmaxf(v, 0.0f);
    agg[i] = 0.0f;
}

// ---- lin2: x_all[:,5,:] (n,128) @ w (128,16) + b -> out ----
__global__ __launch_bounds__(256) void k_lin2(const float* __restrict__ x_all,
                                              const float* __restrict__ w,
                                              const float* __restrict__ b,
                                              float* __restrict__ out) {
    __shared__ float sw[C * DIM_OUT];
    __shared__ float sb[DIM_OUT];
    __shared__ float sx[16][C];
    int tid = threadIdx.x;
    for (int i = tid; i < C * DIM_OUT; i += 256) sw[i] = w[i];
    if (tid < DIM_OUT) sb[tid] = b[tid];
    int node0 = blockIdx.x * 16;
    for (int i = tid; i < 16 * C; i += 256) {
        int nn = node0 + i / C;
        sx[i / C][i & (C - 1)] = (nn < N_NODES) ? x_all[nn * XSTRIDE + 5 * C + (i & (C - 1))] : 0.0f;
    }
    __syncthreads();
    int node = node0 + tid / DIM_OUT;
    int o = tid & (DIM_OUT - 1);
    if (node >= N_NODES) return;
    float acc = sb[o];
    const float* xr = sx[tid / DIM_OUT];
#pragma unroll 8
    for (int c = 0; c < C; c++) acc += xr[c] * sw[c * DIM_OUT + o];
    out[node * DIM_OUT + o] = acc;
}

extern "C" void kernel_launch(void* const* d_in, const int* in_sizes, int n_in,
                              void* d_out, int out_size, void* d_ws, size_t ws_size,
                              hipStream_t stream) {
    const float* x      = (const float*)d_in[0];
    const int*   edge   = (const int*)d_in[1];
    const int*   row    = edge;              // edge_index[0]
    const int*   col    = edge + N_EDGESN;   // edge_index[1]
    const float* lin1_w = (const float*)d_in[2];
    const float* lin1_b = (const float*)d_in[3];
    const float* Wq     = (const float*)d_in[4];
    const float* bq     = (const float*)d_in[5];
    const float* Wk     = (const float*)d_in[6];
    const float* bk     = (const float*)d_in[7];
    const float* Wv     = (const float*)d_in[8];
    const float* bv     = (const float*)d_in[9];
    const float* lin2_w = (const float*)d_in[10];
    const float* lin2_b = (const float*)d_in[11];
    float* outp = (float*)d_out;

    float* ws    = (float*)d_ws;
    float* x_all = ws;                            // n*6*C
    float* Qb    = x_all + (size_t)N_NODES * XSTRIDE;      // n*C
    float* Kb    = Qb + (size_t)N_NODES * C;               // n*5*C
    float* Vb    = Kb + (size_t)N_NODES * LLAYERS * C;     // n*5*C
    float* agg   = Vb + (size_t)N_NODES * LLAYERS * C;     // n*C
    float* deg   = agg + (size_t)N_NODES * C;              // n
    float* nrm   = deg + N_NODES;                          // E_TOT

    const int nc_blocks = (N_NODES * C + 255) / 256;
    k_init<<<nc_blocks, 256, 0, stream>>>(deg, agg);
    k_deg<<<(N_EDGESN + 255) / 256, 256, 0, stream>>>(col, deg);
    k_rsqrt<<<(N_NODES + 255) / 256, 256, 0, stream>>>(deg);
    k_norm<<<(E_TOT + 255) / 256, 256, 0, stream>>>(row, col, deg, nrm);
    k_lin1<<<N_NODES / 2, 256, 0, stream>>>(x, lin1_w, lin1_b, x_all);

    const int attn_blocks = (E_TOT * 64 + 255) / 256;
    for (int l = 0; l < LLAYERS; l++) {
        dim3 g(N_NODES / 2, 1 + 2 * (l + 1));
        k_qkv<<<g, 256, 0, stream>>>(x_all, Wq, bq, Wk, bk, Wv, bv, Qb, Kb, Vb, l);
        switch (l) {
            case 0: k_attn<1><<<attn_blocks, 256, 0, stream>>>(row, col, nrm, Qb, Kb, Vb, agg); break;
            case 1: k_attn<2><<<attn_blocks, 256, 0, stream>>>(row, col, nrm, Qb, Kb, Vb, agg); break;
            case 2: k_attn<3><<<attn_blocks, 256, 0, stream>>>(row, col, nrm, Qb, Kb, Vb, agg); break;
            case 3: k_attn<4><<<attn_blocks, 256, 0, stream>>>(row, col, nrm, Qb, Kb, Vb, agg); break;
            case 4: k_attn<5><<<attn_blocks, 256, 0, stream>>>(row, col, nrm, Qb, Kb, Vb, agg); break;
        }
        k_relu_store<<<nc_blocks, 256, 0, stream>>>(x_all, agg, l);
    }
    k_lin2<<<(N_NODES + 15) / 16, 256, 0, stream>>>(x_all, lin2_w, lin2_b, outp);
}

// Round 2
// 634.401 us; speedup vs baseline: 1.6233x; 1.6233x over previous
//
#include <hip/hip_runtime.h>

#define N_NODES 10000
#define N_EDGESN 160000
#define E_TOT   (N_EDGESN + N_NODES)   // 170000
#define C 128
#define H 8
#define G 16
#define LLAYERS 5
#define NUM_FEAT 14
#define DIM_OUT 16
#define CH 16   // C/H
#define CG 8    // C/G
#define XSTRIDE (6*C)        // x_all row stride (6 layer slots)
#define KVSTRIDE (LLAYERS*2*C)  // per-node KV stride

// ---- counts = 1 (self loop) ----
__global__ void k_zero(int* __restrict__ counts) {
    int i = blockIdx.x * blockDim.x + threadIdx.x;
    if (i < N_NODES) counts[i] = 1;
}

// ---- degree count over original edges (by col) ----
__global__ void k_count(const int* __restrict__ col, int* __restrict__ counts) {
    int e = blockIdx.x * blockDim.x + threadIdx.x;
    if (e < N_EDGESN) atomicAdd(&counts[col[e]], 1);
}

// ---- single-block scan: counts -> exclusive offsets + cursor; dis = rsqrt(counts) ----
__global__ __launch_bounds__(1024) void k_scan(const int* __restrict__ counts,
                                               int* __restrict__ offs, int* __restrict__ cursor,
                                               float* __restrict__ dis) {
    __shared__ int part[1024];
    const int CHK = (N_NODES + 1023) / 1024;   // 10
    int t = threadIdx.x;
    int base = t * CHK;
    int loc[CHK];
    int sum = 0;
#pragma unroll
    for (int i = 0; i < CHK; i++) {
        int idx = base + i;
        int v = (idx < N_NODES) ? counts[idx] : 0;
        loc[i] = sum;
        sum += v;
    }
    part[t] = sum;
    __syncthreads();
    for (int off = 1; off < 1024; off <<= 1) {
        int v = (t >= off) ? part[t - off] : 0;
        __syncthreads();
        part[t] += v;
        __syncthreads();
    }
    int prev = (t > 0) ? part[t - 1] : 0;
#pragma unroll
    for (int i = 0; i < CHK; i++) {
        int idx = base + i;
        if (idx < N_NODES) {
            int o = prev + loc[i];
            offs[idx] = o;
            cursor[idx] = o;
            dis[idx] = rsqrtf((float)counts[idx]);
        }
    }
    if (t == 1023) offs[N_NODES] = part[1023];
}

// ---- scatter edges into dest-sorted CSR; payload = {src, dis[src]} ----
__global__ void k_scatter(const int* __restrict__ row, const int* __restrict__ col,
                          const float* __restrict__ dis,
                          int* __restrict__ cursor, int2* __restrict__ csr) {
    int e = blockIdx.x * blockDim.x + threadIdx.x;
    if (e >= E_TOT) return;
    int r = (e < N_EDGESN) ? row[e] : (e - N_EDGESN);
    int c = (e < N_EDGESN) ? col[e] : (e - N_EDGESN);
    int pos = atomicAdd(&cursor[c], 1);
    int2 pay;
    pay.x = r;
    pay.y = __float_as_int(dis[r]);
    csr[pos] = pay;
}

// ---- lin1: x (n,14) @ w (14,128) + b, relu -> x_all[:,0,:] ----
__global__ __launch_bounds__(256) void k_lin1(const float* __restrict__ x,
                                              const float* __restrict__ w,
                                              const float* __restrict__ b,
                                              float* __restrict__ x_all) {
    __shared__ float sw[NUM_FEAT * C];
    __shared__ float sb[C];
    int tid = threadIdx.x;
    for (int i = tid; i < NUM_FEAT * C; i += 256) sw[i] = w[i];
    if (tid < C) sb[tid] = b[tid];
    __syncthreads();
    int node = blockIdx.x * 2 + tid / C;
    int c = tid & (C - 1);
    if (node >= N_NODES) return;
    const float* xr = x + node * NUM_FEAT;
    float acc = sb[c];
#pragma unroll
    for (int f = 0; f < NUM_FEAT; f++) acc += xr[f] * sw[f * C + c];
    x_all[node * XSTRIDE + c] = fmaxf(acc, 0.0f);
}

// ---- per-node grouped-linear Q/K/V for layer l ----
// grid.y: 0 -> Q (from slot l); 1..l+1 -> K_j (j=y-1); l+2..2l+2 -> V_j
__global__ __launch_bounds__(256) void k_qkv(const float* __restrict__ x_all,
                                             const float* __restrict__ Wq, const float* __restrict__ bq,
                                             const float* __restrict__ Wk, const float* __restrict__ bk,
                                             const float* __restrict__ Wv, const float* __restrict__ bv,
                                             float* __restrict__ Qb, float* __restrict__ KVb, int l) {
    int m = blockIdx.y;
    int mode, j;
    if (m == 0)           { mode = 0; j = l; }
    else if (m <= l + 1)  { mode = 1; j = m - 1; }
    else                  { mode = 2; j = m - l - 2; }
    const float* W = ((mode == 0) ? Wq : (mode == 1) ? Wk : Wv) + l * (G * CG * CG);
    const float* bias = ((mode == 0) ? bq : (mode == 1) ? bk : bv) + l * C;

    __shared__ float sW[G * CG * CG];   // 1024
    __shared__ float sb[C];
    __shared__ float sx[2][C];
    int tid = threadIdx.x;
    for (int i = tid; i < G * CG * CG; i += 256) sW[i] = W[i];
    if (tid < C) sb[tid] = bias[tid];
    int node = blockIdx.x * 2 + tid / C;
    int c = tid & (C - 1);
    if (node < N_NODES) sx[tid / C][c] = x_all[node * XSTRIDE + j * C + c];
    __syncthreads();
    if (node >= N_NODES) return;
    int g = c >> 3, o = c & 7;
    const float* xr = sx[tid / C] + g * CG;
    const float* wg = sW + g * CG * CG;
    float acc = sb[c];
#pragma unroll
    for (int i = 0; i < CG; i++) acc += xr[i] * wg[i * CG + o];
    if (mode == 0)      Qb[node * C + c] = acc;
    else if (mode == 1) KVb[(size_t)node * KVSTRIDE + (j * 2) * C + c] = acc;
    else                KVb[(size_t)node * KVSTRIDE + (j * 2 + 1) * C + c] = acc;
}

// ---- CSR attention: one wave per destination node, register accumulation, no atomics ----
template <int NL>
__global__ __launch_bounds__(256) void k_attn_csr(const int* __restrict__ offs,
                                                  const int2* __restrict__ csr,
                                                  const float* __restrict__ dis,
                                                  const float* __restrict__ Qb,
                                                  const float* __restrict__ KVb,
                                                  float* __restrict__ x_all, int l) {
    int wave = (blockIdx.x * blockDim.x + threadIdx.x) >> 6;
    int lane = threadIdx.x & 63;
    if (wave >= N_NODES) return;
    int d = wave;
    int c0 = lane * 2;
    const float2 q = *(const float2*)(Qb + d * C + c0);
    float disd = dis[d];
    int p0 = offs[d], p1 = offs[d + 1];
    float ox = 0.0f, oy = 0.0f;
    const float scale = 0.25f;   // 1/sqrt(CH=16)
    for (int p = p0; p < p1; p++) {
        int2 pay = csr[p];
        int s = pay.x;
        float nrm = disd * __int_as_float(pay.y);
        const float* kv = KVb + (size_t)s * KVSTRIDE + c0;
        float sc[NL];
#pragma unroll
        for (int j = 0; j < NL; j++) {
            float2 k = *(const float2*)(kv + (j * 2) * C);
            float pr = q.x * k.x + q.y * k.y;
            pr += __shfl_xor(pr, 1);
            pr += __shfl_xor(pr, 2);
            pr += __shfl_xor(pr, 4);   // 8 lanes = one 16-ch head
            sc[j] = pr * scale;
        }
        float mx = sc[0];
#pragma unroll
        for (int j = 1; j < NL; j++) mx = fmaxf(mx, sc[j]);
        float sum = 0.0f;
#pragma unroll
        for (int j = 0; j < NL; j++) { sc[j] = __expf(sc[j] - mx); sum += sc[j]; }
        float inv = nrm / sum;
        float ax = 0.0f, ay = 0.0f;
#pragma unroll
        for (int j = 0; j < NL; j++) {
            float2 v = *(const float2*)(kv + (j * 2 + 1) * C);
            ax += sc[j] * v.x;
            ay += sc[j] * v.y;
        }
        ox += ax * inv;
        oy += ay * inv;
    }
    float* dst = x_all + (size_t)d * XSTRIDE + (l + 1) * C + c0;
    dst[0] = fmaxf(ox, 0.0f);
    dst[1] = fmaxf(oy, 0.0f);
}

// ---- lin2: x_all[:,5,:] (n,128) @ w (128,16) + b -> out ----
__global__ __launch_bounds__(256) void k_lin2(const float* __restrict__ x_all,
                                              const float* __restrict__ w,
                                              const float* __restrict__ b,
                                              float* __restrict__ out) {
    __shared__ float sw[C * DIM_OUT];
    __shared__ float sb[DIM_OUT];
    __shared__ float sx[16][C];
    int tid = threadIdx.x;
    for (int i = tid; i < C * DIM_OUT; i += 256) sw[i] = w[i];
    if (tid < DIM_OUT) sb[tid] = b[tid];
    int node0 = blockIdx.x * 16;
    for (int i = tid; i < 16 * C; i += 256) {
        int nn = node0 + i / C;
        sx[i / C][i & (C - 1)] = (nn < N_NODES) ? x_all[(size_t)nn * XSTRIDE + 5 * C + (i & (C - 1))] : 0.0f;
    }
    __syncthreads();
    int node = node0 + tid / DIM_OUT;
    int o = tid & (DIM_OUT - 1);
    if (node >= N_NODES) return;
    float acc = sb[o];
    const float* xr = sx[tid / DIM_OUT];
#pragma unroll 8
    for (int c = 0; c < C; c++) acc += xr[c] * sw[c * DIM_OUT + o];
    out[node * DIM_OUT + o] = acc;
}

extern "C" void kernel_launch(void* const* d_in, const int* in_sizes, int n_in,
                              void* d_out, int out_size, void* d_ws, size_t ws_size,
                              hipStream_t stream) {
    const float* x      = (const float*)d_in[0];
    const int*   edge   = (const int*)d_in[1];
    const int*   row    = edge;              // edge_index[0]
    const int*   col    = edge + N_EDGESN;   // edge_index[1]
    const float* lin1_w = (const float*)d_in[2];
    const float* lin1_b = (const float*)d_in[3];
    const float* Wq     = (const float*)d_in[4];
    const float* bq     = (const float*)d_in[5];
    const float* Wk     = (const float*)d_in[6];
    const float* bk     = (const float*)d_in[7];
    const float* Wv     = (const float*)d_in[8];
    const float* bv     = (const float*)d_in[9];
    const float* lin2_w = (const float*)d_in[10];
    const float* lin2_b = (const float*)d_in[11];
    float* outp = (float*)d_out;

    float* ws    = (float*)d_ws;
    float* x_all = ws;                                      // n*6*C
    float* Qb    = x_all + (size_t)N_NODES * XSTRIDE;       // n*C
    float* KVb   = Qb + (size_t)N_NODES * C;                // n*5*2*C
    float* dis   = KVb + (size_t)N_NODES * KVSTRIDE;        // n
    int*   counts = (int*)(dis + N_NODES);                  // n
    int*   offs   = counts + N_NODES;                       // n+1
    int*   cursor = offs + N_NODES + 1;                     // n
    int2*  csr    = (int2*)(cursor + N_NODES);              // E_TOT int2

    k_zero<<<(N_NODES + 255) / 256, 256, 0, stream>>>(counts);
    k_count<<<(N_EDGESN + 255) / 256, 256, 0, stream>>>(col, counts);
    k_scan<<<1, 1024, 0, stream>>>(counts, offs, cursor, dis);
    k_scatter<<<(E_TOT + 255) / 256, 256, 0, stream>>>(row, col, dis, cursor, csr);
    k_lin1<<<N_NODES / 2, 256, 0, stream>>>(x, lin1_w, lin1_b, x_all);

    const int attn_blocks = (N_NODES * 64 + 255) / 256;
    for (int l = 0; l < LLAYERS; l++) {
        dim3 g(N_NODES / 2, 1 + 2 * (l + 1));
        k_qkv<<<g, 256, 0, stream>>>(x_all, Wq, bq, Wk, bk, Wv, bv, Qb, KVb, l);
        switch (l) {
            case 0: k_attn_csr<1><<<attn_blocks, 256, 0, stream>>>(offs, csr, dis, Qb, KVb, x_all, l); break;
            case 1: k_attn_csr<2><<<attn_blocks, 256, 0, stream>>>(offs, csr, dis, Qb, KVb, x_all, l); break;
            case 2: k_attn_csr<3><<<attn_blocks, 256, 0, stream>>>(offs, csr, dis, Qb, KVb, x_all, l); break;
            case 3: k_attn_csr<4><<<attn_blocks, 256, 0, stream>>>(offs, csr, dis, Qb, KVb, x_all, l); break;
            case 4: k_attn_csr<5><<<attn_blocks, 256, 0, stream>>>(offs, csr, dis, Qb, KVb, x_all, l); break;
        }
    }
    k_lin2<<<(N_NODES + 15) / 16, 256, 0, stream>>>(x_all, lin2_w, lin2_b, outp);
}

// Round 3
// 587.250 us; speedup vs baseline: 1.7536x; 1.0803x over previous
//
#include <hip/hip_runtime.h>

#define N_NODES 10000
#define N_EDGESN 160000
#define E_TOT   (N_EDGESN + N_NODES)   // 170000
#define C 128
#define H 8
#define G 16
#define LLAYERS 5
#define NUM_FEAT 14
#define DIM_OUT 16
#define CH 16   // C/H
#define CG 8    // C/G
#define XSTRIDE (6*C)        // x_all row stride (6 layer slots)

// ---- counts = 1 (self loop) ----
__global__ void k_zero(int* __restrict__ counts) {
    int i = blockIdx.x * blockDim.x + threadIdx.x;
    if (i < N_NODES) counts[i] = 1;
}

// ---- degree count over original edges (by col) ----
__global__ void k_count(const int* __restrict__ col, int* __restrict__ counts) {
    int e = blockIdx.x * blockDim.x + threadIdx.x;
    if (e < N_EDGESN) atomicAdd(&counts[col[e]], 1);
}

// ---- single-block scan: counts -> exclusive offsets + cursor; dis = rsqrt(counts) ----
__global__ __launch_bounds__(1024) void k_scan(const int* __restrict__ counts,
                                               int* __restrict__ offs, int* __restrict__ cursor,
                                               float* __restrict__ dis) {
    __shared__ int part[1024];
    const int CHK = (N_NODES + 1023) / 1024;   // 10
    int t = threadIdx.x;
    int base = t * CHK;
    int loc[CHK];
    int sum = 0;
#pragma unroll
    for (int i = 0; i < CHK; i++) {
        int idx = base + i;
        int v = (idx < N_NODES) ? counts[idx] : 0;
        loc[i] = sum;
        sum += v;
    }
    part[t] = sum;
    __syncthreads();
    for (int off = 1; off < 1024; off <<= 1) {
        int v = (t >= off) ? part[t - off] : 0;
        __syncthreads();
        part[t] += v;
        __syncthreads();
    }
    int prev = (t > 0) ? part[t - 1] : 0;
#pragma unroll
    for (int i = 0; i < CHK; i++) {
        int idx = base + i;
        if (idx < N_NODES) {
            int o = prev + loc[i];
            offs[idx] = o;
            cursor[idx] = o;
            dis[idx] = rsqrtf((float)counts[idx]);
        }
    }
    if (t == 1023) offs[N_NODES] = part[1023];
}

// ---- scatter edges into dest-sorted CSR; payload = {src, dis[src]} ----
__global__ void k_scatter(const int* __restrict__ row, const int* __restrict__ col,
                          const float* __restrict__ dis,
                          int* __restrict__ cursor, int2* __restrict__ csr) {
    int e = blockIdx.x * blockDim.x + threadIdx.x;
    if (e >= E_TOT) return;
    int r = (e < N_EDGESN) ? row[e] : (e - N_EDGESN);
    int c = (e < N_EDGESN) ? col[e] : (e - N_EDGESN);
    int pos = atomicAdd(&cursor[c], 1);
    int2 pay;
    pay.x = r;
    pay.y = __float_as_int(dis[r]);
    csr[pos] = pay;
}

// ---- lin1: x (n,14) @ w (14,128) + b, relu -> x_all[:,0,:] ----
__global__ __launch_bounds__(256) void k_lin1(const float* __restrict__ x,
                                              const float* __restrict__ w,
                                              const float* __restrict__ b,
                                              float* __restrict__ x_all) {
    __shared__ float sw[NUM_FEAT * C];
    __shared__ float sb[C];
    int tid = threadIdx.x;
    for (int i = tid; i < NUM_FEAT * C; i += 256) sw[i] = w[i];
    if (tid < C) sb[tid] = b[tid];
    __syncthreads();
    int node = blockIdx.x * 2 + tid / C;
    int c = tid & (C - 1);
    if (node >= N_NODES) return;
    const float* xr = x + node * NUM_FEAT;
    float acc = sb[c];
#pragma unroll
    for (int f = 0; f < NUM_FEAT; f++) acc += xr[f] * sw[f * C + c];
    x_all[node * XSTRIDE + c] = fmaxf(acc, 0.0f);
}

// ---- per-node grouped-linear Q/K/V for layer l, COMPACT per-layer KV stride ----
// grid.y: 0 -> Q (from slot l); 1..l+1 -> K_j (j=y-1); l+2..2l+2 -> V_j
__global__ __launch_bounds__(256) void k_qkv(const float* __restrict__ x_all,
                                             const float* __restrict__ Wq, const float* __restrict__ bq,
                                             const float* __restrict__ Wk, const float* __restrict__ bk,
                                             const float* __restrict__ Wv, const float* __restrict__ bv,
                                             float* __restrict__ Qb, float* __restrict__ KVb, int l) {
    int m = blockIdx.y;
    int mode, j;
    if (m == 0)           { mode = 0; j = l; }
    else if (m <= l + 1)  { mode = 1; j = m - 1; }
    else                  { mode = 2; j = m - l - 2; }
    const float* W = ((mode == 0) ? Wq : (mode == 1) ? Wk : Wv) + l * (G * CG * CG);
    const float* bias = ((mode == 0) ? bq : (mode == 1) ? bk : bv) + l * C;
    const int kvstride = (l + 1) * 2 * C;

    __shared__ float sW[G * CG * CG];   // 1024
    __shared__ float sb[C];
    __shared__ float sx[2][C];
    int tid = threadIdx.x;
    for (int i = tid; i < G * CG * CG; i += 256) sW[i] = W[i];
    if (tid < C) sb[tid] = bias[tid];
    int node = blockIdx.x * 2 + tid / C;
    int c = tid & (C - 1);
    if (node < N_NODES) sx[tid / C][c] = x_all[node * XSTRIDE + j * C + c];
    __syncthreads();
    if (node >= N_NODES) return;
    int g = c >> 3, o = c & 7;
    const float* xr = sx[tid / C] + g * CG;
    const float* wg = sW + g * CG * CG;
    float acc = sb[c];
#pragma unroll
    for (int i = 0; i < CG; i++) acc += xr[i] * wg[i * CG + o];
    if (mode == 0)      Qb[node * C + c] = acc;
    else if (mode == 1) KVb[(size_t)node * kvstride + (j * 2) * C + c] = acc;
    else                KVb[(size_t)node * kvstride + (j * 2 + 1) * C + c] = acc;
}

// ---- per-edge contribution (one edge), lane owns 2 channels ----
template <int NL>
__device__ __forceinline__ void edge_contrib(const float2 q, float disd,
                                             const float* __restrict__ KVb,
                                             int2 pay, int c0,
                                             float& ox, float& oy) {
    const float scale = 0.25f;   // 1/sqrt(CH=16)
    int s = pay.x;
    float nrm = disd * __int_as_float(pay.y);
    const float* kv = KVb + (size_t)s * (NL * 2 * C) + c0;
    float sc[NL];
#pragma unroll
    for (int j = 0; j < NL; j++) {
        float2 k = *(const float2*)(kv + (j * 2) * C);
        float pr = q.x * k.x + q.y * k.y;
        pr += __shfl_xor(pr, 1);
        pr += __shfl_xor(pr, 2);
        pr += __shfl_xor(pr, 4);   // 8 lanes = one 16-ch head
        sc[j] = pr * scale;
    }
    float mx = sc[0];
#pragma unroll
    for (int j = 1; j < NL; j++) mx = fmaxf(mx, sc[j]);
    float sum = 0.0f;
#pragma unroll
    for (int j = 0; j < NL; j++) { sc[j] = __expf(sc[j] - mx); sum += sc[j]; }
    float inv = nrm / sum;
    float ax = 0.0f, ay = 0.0f;
#pragma unroll
    for (int j = 0; j < NL; j++) {
        float2 v = *(const float2*)(kv + (j * 2 + 1) * C);
        ax += sc[j] * v.x;
        ay += sc[j] * v.y;
    }
    ox += ax * inv;
    oy += ay * inv;
}

// ---- CSR attention: 4 waves per destination node, pairwise-unrolled, LDS reduce ----
template <int NL>
__global__ __launch_bounds__(256) void k_attn_csr(const int* __restrict__ offs,
                                                  const int2* __restrict__ csr,
                                                  const float* __restrict__ dis,
                                                  const float* __restrict__ Qb,
                                                  const float* __restrict__ KVb,
                                                  float* __restrict__ x_all, int l) {
    __shared__ float red[4][C];
    int d = blockIdx.x;
    int w = threadIdx.x >> 6;       // wave 0..3
    int lane = threadIdx.x & 63;
    int c0 = lane * 2;
    const float2 q = *(const float2*)(Qb + d * C + c0);
    float disd = dis[d];
    int p0 = offs[d], p1 = offs[d + 1];
    float ox = 0.0f, oy = 0.0f;
    int p = p0 + w;
    // pairs (p, p+4) for ILP; conditions are wave-uniform
    for (; p + 4 < p1; p += 8) {
        int2 payA = csr[p];
        int2 payB = csr[p + 4];
        edge_contrib<NL>(q, disd, KVb, payA, c0, ox, oy);
        edge_contrib<NL>(q, disd, KVb, payB, c0, ox, oy);
    }
    if (p < p1) {
        int2 pay = csr[p];
        edge_contrib<NL>(q, disd, KVb, pay, c0, ox, oy);
    }
    red[w][c0] = ox;
    red[w][c0 + 1] = oy;
    __syncthreads();
    if (threadIdx.x < C) {
        int c = threadIdx.x;
        float v = red[0][c] + red[1][c] + red[2][c] + red[3][c];
        x_all[(size_t)d * XSTRIDE + (l + 1) * C + c] = fmaxf(v, 0.0f);
    }
}

// ---- lin2: x_all[:,5,:] (n,128) @ w (128,16) + b -> out ----
__global__ __launch_bounds__(256) void k_lin2(const float* __restrict__ x_all,
                                              const float* __restrict__ w,
                                              const float* __restrict__ b,
                                              float* __restrict__ out) {
    __shared__ float sw[C * DIM_OUT];
    __shared__ float sb[DIM_OUT];
    __shared__ float sx[16][C];
    int tid = threadIdx.x;
    for (int i = tid; i < C * DIM_OUT; i += 256) sw[i] = w[i];
    if (tid < DIM_OUT) sb[tid] = b[tid];
    int node0 = blockIdx.x * 16;
    for (int i = tid; i < 16 * C; i += 256) {
        int nn = node0 + i / C;
        sx[i / C][i & (C - 1)] = (nn < N_NODES) ? x_all[(size_t)nn * XSTRIDE + 5 * C + (i & (C - 1))] : 0.0f;
    }
    __syncthreads();
    int node = node0 + tid / DIM_OUT;
    int o = tid & (DIM_OUT - 1);
    if (node >= N_NODES) return;
    float acc = sb[o];
    const float* xr = sx[tid / DIM_OUT];
#pragma unroll 8
    for (int c = 0; c < C; c++) acc += xr[c] * sw[c * DIM_OUT + o];
    out[node * DIM_OUT + o] = acc;
}

extern "C" void kernel_launch(void* const* d_in, const int* in_sizes, int n_in,
                              void* d_out, int out_size, void* d_ws, size_t ws_size,
                              hipStream_t stream) {
    const float* x      = (const float*)d_in[0];
    const int*   edge   = (const int*)d_in[1];
    const int*   row    = edge;              // edge_index[0]
    const int*   col    = edge + N_EDGESN;   // edge_index[1]
    const float* lin1_w = (const float*)d_in[2];
    const float* lin1_b = (const float*)d_in[3];
    const float* Wq     = (const float*)d_in[4];
    const float* bq     = (const float*)d_in[5];
    const float* Wk     = (const float*)d_in[6];
    const float* bk     = (const float*)d_in[7];
    const float* Wv     = (const float*)d_in[8];
    const float* bv     = (const float*)d_in[9];
    const float* lin2_w = (const float*)d_in[10];
    const float* lin2_b = (const float*)d_in[11];
    float* outp = (float*)d_out;

    float* ws    = (float*)d_ws;
    float* x_all = ws;                                      // n*6*C
    float* Qb    = x_all + (size_t)N_NODES * XSTRIDE;       // n*C
    float* KVb   = Qb + (size_t)N_NODES * C;                // n*10*C max
    float* dis   = KVb + (size_t)N_NODES * LLAYERS * 2 * C; // n
    int*   counts = (int*)(dis + N_NODES);                  // n
    int*   offs   = counts + N_NODES;                       // n+1
    int*   cursor = offs + N_NODES + 1;                     // n
    int2*  csr    = (int2*)(cursor + N_NODES);              // E_TOT int2

    k_zero<<<(N_NODES + 255) / 256, 256, 0, stream>>>(counts);
    k_count<<<(N_EDGESN + 255) / 256, 256, 0, stream>>>(col, counts);
    k_scan<<<1, 1024, 0, stream>>>(counts, offs, cursor, dis);
    k_scatter<<<(E_TOT + 255) / 256, 256, 0, stream>>>(row, col, dis, cursor, csr);
    k_lin1<<<N_NODES / 2, 256, 0, stream>>>(x, lin1_w, lin1_b, x_all);

    for (int l = 0; l < LLAYERS; l++) {
        dim3 g(N_NODES / 2, 1 + 2 * (l + 1));
        k_qkv<<<g, 256, 0, stream>>>(x_all, Wq, bq, Wk, bk, Wv, bv, Qb, KVb, l);
        switch (l) {
            case 0: k_attn_csr<1><<<N_NODES, 256, 0, stream>>>(offs, csr, dis, Qb, KVb, x_all, l); break;
            case 1: k_attn_csr<2><<<N_NODES, 256, 0, stream>>>(offs, csr, dis, Qb, KVb, x_all, l); break;
            case 2: k_attn_csr<3><<<N_NODES, 256, 0, stream>>>(offs, csr, dis, Qb, KVb, x_all, l); break;
            case 3: k_attn_csr<4><<<N_NODES, 256, 0, stream>>>(offs, csr, dis, Qb, KVb, x_all, l); break;
            case 4: k_attn_csr<5><<<N_NODES, 256, 0, stream>>>(offs, csr, dis, Qb, KVb, x_all, l); break;
        }
    }
    k_lin2<<<(N_NODES + 15) / 16, 256, 0, stream>>>(x_all, lin2_w, lin2_b, outp);
}

// Round 4
// 432.243 us; speedup vs baseline: 2.3825x; 1.3586x over previous
//
#include <hip/hip_runtime.h>

#define N_NODES 10000
#define N_EDGESN 160000
#define E_TOT   (N_EDGESN + N_NODES)   // 170000
#define C 128
#define H 8
#define G 16
#define LLAYERS 5
#define NUM_FEAT 14
#define DIM_OUT 16
#define CH 16   // C/H
#define CG 8    // C/G
#define XSTRIDE (6*C)        // x_all row stride (6 layer slots)

// ---- counts = 1 (self loop) ----
__global__ void k_zero(int* __restrict__ counts) {
    int i = blockIdx.x * blockDim.x + threadIdx.x;
    if (i < N_NODES) counts[i] = 1;
}

// ---- degree count over original edges (by col) ----
__global__ void k_count(const int* __restrict__ col, int* __restrict__ counts) {
    int e = blockIdx.x * blockDim.x + threadIdx.x;
    if (e < N_EDGESN) atomicAdd(&counts[col[e]], 1);
}

// ---- single-block scan: counts -> exclusive offsets + cursor; dis = rsqrt(counts) ----
__global__ __launch_bounds__(1024) void k_scan(const int* __restrict__ counts,
                                               int* __restrict__ offs, int* __restrict__ cursor,
                                               float* __restrict__ dis) {
    __shared__ int part[1024];
    const int CHK = (N_NODES + 1023) / 1024;   // 10
    int t = threadIdx.x;
    int base = t * CHK;
    int loc[CHK];
    int sum = 0;
#pragma unroll
    for (int i = 0; i < CHK; i++) {
        int idx = base + i;
        int v = (idx < N_NODES) ? counts[idx] : 0;
        loc[i] = sum;
        sum += v;
    }
    part[t] = sum;
    __syncthreads();
    for (int off = 1; off < 1024; off <<= 1) {
        int v = (t >= off) ? part[t - off] : 0;
        __syncthreads();
        part[t] += v;
        __syncthreads();
    }
    int prev = (t > 0) ? part[t - 1] : 0;
#pragma unroll
    for (int i = 0; i < CHK; i++) {
        int idx = base + i;
        if (idx < N_NODES) {
            int o = prev + loc[i];
            offs[idx] = o;
            cursor[idx] = o;
            dis[idx] = rsqrtf((float)counts[idx]);
        }
    }
    if (t == 1023) offs[N_NODES] = part[1023];
}

// ---- scatter edges into dest-sorted CSR; payload = {src, dis[src]} ----
__global__ void k_scatter(const int* __restrict__ row, const int* __restrict__ col,
                          const float* __restrict__ dis,
                          int* __restrict__ cursor, int2* __restrict__ csr) {
    int e = blockIdx.x * blockDim.x + threadIdx.x;
    if (e >= E_TOT) return;
    int r = (e < N_EDGESN) ? row[e] : (e - N_EDGESN);
    int c = (e < N_EDGESN) ? col[e] : (e - N_EDGESN);
    int pos = atomicAdd(&cursor[c], 1);
    int2 pay;
    pay.x = r;
    pay.y = __float_as_int(dis[r]);
    csr[pos] = pay;
}

// ---- lin1: x (n,14) @ w (14,128) + b, relu -> x_all[:,0,:] ----
__global__ __launch_bounds__(256) void k_lin1(const float* __restrict__ x,
                                              const float* __restrict__ w,
                                              const float* __restrict__ b,
                                              float* __restrict__ x_all) {
    __shared__ float sw[NUM_FEAT * C];
    __shared__ float sb[C];
    int tid = threadIdx.x;
    for (int i = tid; i < NUM_FEAT * C; i += 256) sw[i] = w[i];
    if (tid < C) sb[tid] = b[tid];
    __syncthreads();
    int node = blockIdx.x * 2 + tid / C;
    int c = tid & (C - 1);
    if (node >= N_NODES) return;
    const float* xr = x + node * NUM_FEAT;
    float acc = sb[c];
#pragma unroll
    for (int f = 0; f < NUM_FEAT; f++) acc += xr[f] * sw[f * C + c];
    x_all[node * XSTRIDE + c] = fmaxf(acc, 0.0f);
}

// ---- fused attention layer: gather x, compute Q/K/V on the fly ----
// One block (4 waves) per destination node. Lane owns output channels c0,c0+1.
// x for a group (8 ch) is assembled across its 4 lanes via shfl butterfly;
// per-lane weight registers are pre-permuted to match butterfly order.
template <int NL>
__global__ __launch_bounds__(256) void k_attn_fly(const int* __restrict__ offs,
                                                  const int2* __restrict__ csr,
                                                  const float* __restrict__ dis,
                                                  const float* __restrict__ Wq, const float* __restrict__ bq,
                                                  const float* __restrict__ Wk, const float* __restrict__ bk,
                                                  const float* __restrict__ Wv, const float* __restrict__ bv,
                                                  float* __restrict__ x_all) {
    const int l = NL - 1;
    __shared__ float red[4][C];
    int d = blockIdx.x;
    int w = threadIdx.x >> 6;
    int lane = threadIdx.x & 63;
    int c0 = lane * 2;
    int j4 = lane & 3;      // position within 4-lane x-group
    int g = lane >> 2;      // channel group 0..15
    int o0 = c0 & 7;        // output col within group (=2*j4)

    // butterfly-permuted absolute input rows: own, ^1, ^2, ^3 pairs
    int rr[8];
    rr[0] = 2 * j4;       rr[1] = rr[0] + 1;
    rr[2] = 2 * (j4 ^ 1); rr[3] = rr[2] + 1;
    rr[4] = 2 * (j4 ^ 2); rr[5] = rr[4] + 1;
    rr[6] = 2 * (j4 ^ 3); rr[7] = rr[6] + 1;

    const float* Wq_g = Wq + l * (G * CG * CG) + g * (CG * CG);
    const float* Wk_g = Wk + l * (G * CG * CG) + g * (CG * CG);
    const float* Wv_g = Wv + l * (G * CG * CG) + g * (CG * CG);

    float wkA[8], wkB[8], wvA[8], wvB[8];
#pragma unroll
    for (int p = 0; p < 8; p++) {
        wkA[p] = Wk_g[rr[p] * CG + o0];
        wkB[p] = Wk_g[rr[p] * CG + o0 + 1];
        wvA[p] = Wv_g[rr[p] * CG + o0];
        wvB[p] = Wv_g[rr[p] * CG + o0 + 1];
    }
    float bk0 = bk[l * C + c0], bk1 = bk[l * C + c0 + 1];
    float bv0 = bv[l * C + c0], bv1 = bv[l * C + c0 + 1];

    // q for this destination from x_all[d][l]
    float qx, qy;
    {
        float2 xd = *(const float2*)(x_all + (size_t)d * XSTRIDE + l * C + c0);
        float xa[8];
        xa[0] = xd.x;                  xa[1] = xd.y;
        xa[2] = __shfl_xor(xa[0], 1);  xa[3] = __shfl_xor(xa[1], 1);
        xa[4] = __shfl_xor(xa[0], 2);  xa[5] = __shfl_xor(xa[1], 2);
        xa[6] = __shfl_xor(xa[2], 2);  xa[7] = __shfl_xor(xa[3], 2);
        qx = bq[l * C + c0];
        qy = bq[l * C + c0 + 1];
#pragma unroll
        for (int p = 0; p < 8; p++) {
            qx += xa[p] * Wq_g[rr[p] * CG + o0];
            qy += xa[p] * Wq_g[rr[p] * CG + o0 + 1];
        }
    }

    float disd = dis[d];
    int p0 = offs[d], p1 = offs[d + 1];
    float ox = 0.0f, oy = 0.0f;
    const float scale = 0.25f;   // 1/sqrt(CH=16)
    for (int p = p0 + w; p < p1; p += 4) {
        int2 pay = csr[p];
        int s = pay.x;
        float nrm = disd * __int_as_float(pay.y);
        const float* xsrc = x_all + (size_t)s * XSTRIDE + c0;
        float sc[NL], vxr[NL], vyr[NL];
#pragma unroll
        for (int t = 0; t < NL; t++) {
            float2 xv = *(const float2*)(xsrc + t * C);
            float xa0 = xv.x, xa1 = xv.y;
            float xa2 = __shfl_xor(xa0, 1), xa3 = __shfl_xor(xa1, 1);
            float xa4 = __shfl_xor(xa0, 2), xa5 = __shfl_xor(xa1, 2);
            float xa6 = __shfl_xor(xa2, 2), xa7 = __shfl_xor(xa3, 2);
            float k0 = bk0 + xa0 * wkA[0] + xa1 * wkA[1] + xa2 * wkA[2] + xa3 * wkA[3]
                            + xa4 * wkA[4] + xa5 * wkA[5] + xa6 * wkA[6] + xa7 * wkA[7];
            float k1 = bk1 + xa0 * wkB[0] + xa1 * wkB[1] + xa2 * wkB[2] + xa3 * wkB[3]
                            + xa4 * wkB[4] + xa5 * wkB[5] + xa6 * wkB[6] + xa7 * wkB[7];
            float v0 = bv0 + xa0 * wvA[0] + xa1 * wvA[1] + xa2 * wvA[2] + xa3 * wvA[3]
                            + xa4 * wvA[4] + xa5 * wvA[5] + xa6 * wvA[6] + xa7 * wvA[7];
            float v1 = bv1 + xa0 * wvB[0] + xa1 * wvB[1] + xa2 * wvB[2] + xa3 * wvB[3]
                            + xa4 * wvB[4] + xa5 * wvB[5] + xa6 * wvB[6] + xa7 * wvB[7];
            float pr = qx * k0 + qy * k1;
            pr += __shfl_xor(pr, 1);
            pr += __shfl_xor(pr, 2);
            pr += __shfl_xor(pr, 4);   // 8 lanes = one 16-ch head
            sc[t] = pr * scale;
            vxr[t] = v0;
            vyr[t] = v1;
        }
        float mx = sc[0];
#pragma unroll
        for (int t = 1; t < NL; t++) mx = fmaxf(mx, sc[t]);
        float sum = 0.0f;
#pragma unroll
        for (int t = 0; t < NL; t++) { sc[t] = __expf(sc[t] - mx); sum += sc[t]; }
        float inv = nrm / sum;
        float ax = 0.0f, ay = 0.0f;
#pragma unroll
        for (int t = 0; t < NL; t++) { ax += sc[t] * vxr[t]; ay += sc[t] * vyr[t]; }
        ox += ax * inv;
        oy += ay * inv;
    }
    red[w][c0] = ox;
    red[w][c0 + 1] = oy;
    __syncthreads();
    if (threadIdx.x < C) {
        int c = threadIdx.x;
        float v = red[0][c] + red[1][c] + red[2][c] + red[3][c];
        x_all[(size_t)d * XSTRIDE + (l + 1) * C + c] = fmaxf(v, 0.0f);
    }
}

// ---- lin2: x_all[:,5,:] (n,128) @ w (128,16) + b -> out ----
__global__ __launch_bounds__(256) void k_lin2(const float* __restrict__ x_all,
                                              const float* __restrict__ w,
                                              const float* __restrict__ b,
                                              float* __restrict__ out) {
    __shared__ float sw[C * DIM_OUT];
    __shared__ float sb[DIM_OUT];
    __shared__ float sx[16][C];
    int tid = threadIdx.x;
    for (int i = tid; i < C * DIM_OUT; i += 256) sw[i] = w[i];
    if (tid < DIM_OUT) sb[tid] = b[tid];
    int node0 = blockIdx.x * 16;
    for (int i = tid; i < 16 * C; i += 256) {
        int nn = node0 + i / C;
        sx[i / C][i & (C - 1)] = (nn < N_NODES) ? x_all[(size_t)nn * XSTRIDE + 5 * C + (i & (C - 1))] : 0.0f;
    }
    __syncthreads();
    int node = node0 + tid / DIM_OUT;
    int o = tid & (DIM_OUT - 1);
    if (node >= N_NODES) return;
    float acc = sb[o];
    const float* xr = sx[tid / DIM_OUT];
#pragma unroll 8
    for (int c = 0; c < C; c++) acc += xr[c] * sw[c * DIM_OUT + o];
    out[node * DIM_OUT + o] = acc;
}

extern "C" void kernel_launch(void* const* d_in, const int* in_sizes, int n_in,
                              void* d_out, int out_size, void* d_ws, size_t ws_size,
                              hipStream_t stream) {
    const float* x      = (const float*)d_in[0];
    const int*   edge   = (const int*)d_in[1];
    const int*   row    = edge;              // edge_index[0]
    const int*   col    = edge + N_EDGESN;   // edge_index[1]
    const float* lin1_w = (const float*)d_in[2];
    const float* lin1_b = (const float*)d_in[3];
    const float* Wq     = (const float*)d_in[4];
    const float* bq     = (const float*)d_in[5];
    const float* Wk     = (const float*)d_in[6];
    const float* bk     = (const float*)d_in[7];
    const float* Wv     = (const float*)d_in[8];
    const float* bv     = (const float*)d_in[9];
    const float* lin2_w = (const float*)d_in[10];
    const float* lin2_b = (const float*)d_in[11];
    float* outp = (float*)d_out;

    float* ws    = (float*)d_ws;
    float* x_all = ws;                                      // n*6*C
    float* dis   = x_all + (size_t)N_NODES * XSTRIDE;       // n
    int*   counts = (int*)(dis + N_NODES);                  // n
    int*   offs   = counts + N_NODES;                       // n+1
    int*   cursor = offs + N_NODES + 1;                     // n
    int2*  csr    = (int2*)(cursor + N_NODES);              // E_TOT int2

    k_zero<<<(N_NODES + 255) / 256, 256, 0, stream>>>(counts);
    k_count<<<(N_EDGESN + 255) / 256, 256, 0, stream>>>(col, counts);
    k_scan<<<1, 1024, 0, stream>>>(counts, offs, cursor, dis);
    k_scatter<<<(E_TOT + 255) / 256, 256, 0, stream>>>(row, col, dis, cursor, csr);
    k_lin1<<<N_NODES / 2, 256, 0, stream>>>(x, lin1_w, lin1_b, x_all);

    for (int l = 0; l < LLAYERS; l++) {
        switch (l) {
            case 0: k_attn_fly<1><<<N_NODES, 256, 0, stream>>>(offs, csr, dis, Wq, bq, Wk, bk, Wv, bv, x_all); break;
            case 1: k_attn_fly<2><<<N_NODES, 256, 0, stream>>>(offs, csr, dis, Wq, bq, Wk, bk, Wv, bv, x_all); break;
            case 2: k_attn_fly<3><<<N_NODES, 256, 0, stream>>>(offs, csr, dis, Wq, bq, Wk, bk, Wv, bv, x_all); break;
            case 3: k_attn_fly<4><<<N_NODES, 256, 0, stream>>>(offs, csr, dis, Wq, bq, Wk, bk, Wv, bv, x_all); break;
            case 4: k_attn_fly<5><<<N_NODES, 256, 0, stream>>>(offs, csr, dis, Wq, bq, Wk, bk, Wv, bv, x_all); break;
        }
    }
    k_lin2<<<(N_NODES + 15) / 16, 256, 0, stream>>>(x_all, lin2_w, lin2_b, outp);
}